// Round 4
// baseline (102.662 us; speedup 1.0000x reference)
//
#include <hip/hip_runtime.h>

#define HIDDEN 64
#define SEQLEN 96
#define NB 10
#define BATCH 16384
#define NCLASS 2
#define KTOT (HIDDEN * NB)   // 640
#define NKC (KTOT / 32)      // 20 K-chunks of 32
#define MT 32                // batch rows per block (2 M-tiles of 16)
#define NW 4                 // waves per block = K-split factor
#define KCW (NKC / NW)       // 5 K-chunks per wave
#define HSS 33               // hs stride (pad 32->33: kills 4-way quad conflict)
#define CRS 66               // Cred stride (pad 64->66: atomic conflicts -> 2-way free)

typedef __attribute__((ext_vector_type(8))) short bf16x8;
typedef __attribute__((ext_vector_type(4))) float f32x4;

__device__ __forceinline__ float fast_tanh(float x) {
    float e = __expf(x + x);
    float r = __builtin_amdgcn_rcpf(e + 1.0f);
    return fmaf(-2.0f, r, 1.0f);
}

__device__ __forceinline__ unsigned bf16_rn(float f) {
    unsigned u = __float_as_uint(f);
    return (u + 0x8000u) >> 16;
}

// Repack Wc (HIDDEN,HIDDEN,NB) fp32 -> bf16 B-fragments for 16x16x32 MFMA.
// Wp[((kcg*4 + nt)*64 + lane)*8 + j] = bf16(W[q][o]),
//   q = kcg*32 + (lane>>4)*8 + j, o = nt*16 + (lane&15), W[q][o] = Wc[q/10][o][q%10]
__global__ __launch_bounds__(256) void prep_wb(const float* __restrict__ Wc,
                                               ushort* __restrict__ Wp) {
    int e = blockIdx.x * 256 + threadIdx.x;      // 0..40959
    int j = e & 7;
    int lane = (e >> 3) & 63;
    int rest = e >> 9;
    int nt = rest & 3;
    int kcg = rest >> 2;
    int q = kcg * 32 + (lane >> 4) * 8 + j;
    int o = nt * 16 + (lane & 15);
    int i = q / 10;
    int k = q - i * 10;
    Wp[e] = (ushort)bf16_rn(Wc[i * (HIDDEN * NB) + o * NB + k]);
}

__global__ __launch_bounds__(256, 4) void kan_mfma(
    const float* __restrict__ x,    // (B, SEQLEN)
    const float* __restrict__ Wx,   // (1, HIDDEN, NB)
    const float* __restrict__ ax, const float* __restrict__ cx,  // (1, NB)
    const float* __restrict__ ac,   // (HIDDEN, NB) flat == q-order
    const float* __restrict__ cc,   // (HIDDEN, NB)
    const float* __restrict__ Wout, // (HIDDEN, NCLASS)
    const ushort* __restrict__ Wp,  // packed B-fragments (d_ws)
    float* __restrict__ out)        // (B, NCLASS)
{
    __shared__ float hs[65 * HSS];       // h[i][m], m=0..31; +1 guard row
    __shared__ float Cred[MT * CRS];     // K-split reduction of C
    __shared__ float outb[MT * NCLASS];

    const int lane = threadIdx.x;        // 0..63
    const int w    = threadIdx.y;        // 0..3  (K-split wave id)
    const int tid  = w * 64 + lane;
    const int bb   = blockIdx.x * MT;

    for (int idx = tid; idx < MT * CRS; idx += 256) Cred[idx] = 0.0f;

    // ---- stage A: h[i][m] = tanh(Wx_i . t_m); recurrence dead -> only x[:,95]
    {
        const int sm = tid & 31;         // batch row 0..31
        const int sg = tid >> 5;         // i-group: 8 i's per thread
        const float u = x[(bb + sm) * SEQLEN + (SEQLEN - 1)];
        float t[NB];
#pragma unroll
        for (int k = 0; k < NB; ++k)
            t[k] = fast_tanh(fmaf(ax[k], u, cx[k]));
#pragma unroll
        for (int r = 0; r < 8; ++r) {
            const int i = sg * 8 + r;
            const float* wxr = Wx + i * NB;
            float hx = 0.0f;
#pragma unroll
            for (int k = 0; k < NB; ++k)
                hx = fmaf(wxr[k], t[k], hx);
            hs[i * HSS + sm] = fast_tanh(hx);
        }
    }
    __syncthreads();

    // ---- stage B: GEMM 16384x640x64; wave w owns K-chunks [w*5, w*5+5),
    //      2 M-tiles per wave (rows m and 16+m) sharing B-fragments.
    const int m    = lane & 15;
    const int quad = lane >> 4;
    f32x4 a00 = {0,0,0,0}, a01 = {0,0,0,0}, a02 = {0,0,0,0}, a03 = {0,0,0,0};
    f32x4 a10 = {0,0,0,0}, a11 = {0,0,0,0}, a12 = {0,0,0,0}, a13 = {0,0,0,0};

#pragma unroll
    for (int c = 0; c < KCW; ++c) {
        const int kcg = w * KCW + c;
        const int q0  = kcg * 32 + quad * 8;
        const int i0  = q0 / 10;
        const int r0  = q0 - i0 * 10;
        const float h0a = hs[i0 * HSS + m];
        const float h1a = hs[(i0 + 1) * HSS + m];
        const float h0b = hs[i0 * HSS + 16 + m];
        const float h1b = hs[(i0 + 1) * HSS + 16 + m];
        const float4 av0 = *(const float4*)(ac + q0);
        const float4 av1 = *(const float4*)(ac + q0 + 4);
        const float4 cv0 = *(const float4*)(cc + q0);
        const float4 cv1 = *(const float4*)(cc + q0 + 4);
        const float av[8] = {av0.x,av0.y,av0.z,av0.w,av1.x,av1.y,av1.z,av1.w};
        const float cv[8] = {cv0.x,cv0.y,cv0.z,cv0.w,cv1.x,cv1.y,cv1.z,cv1.w};

        union { unsigned u[4]; bf16x8 v; } af0, af1;
#pragma unroll
        for (int jj = 0; jj < 4; ++jj) {
            const int j0 = 2 * jj, j1 = 2 * jj + 1;
            const float hA0 = (r0 + j0 >= 10) ? h1a : h0a;
            const float hA1 = (r0 + j1 >= 10) ? h1a : h0a;
            const float hB0 = (r0 + j0 >= 10) ? h1b : h0b;
            const float hB1 = (r0 + j1 >= 10) ? h1b : h0b;
            const float pA0 = fast_tanh(fmaf(av[j0], hA0, cv[j0]));
            const float pA1 = fast_tanh(fmaf(av[j1], hA1, cv[j1]));
            const float pB0 = fast_tanh(fmaf(av[j0], hB0, cv[j0]));
            const float pB1 = fast_tanh(fmaf(av[j1], hB1, cv[j1]));
            af0.u[jj] = bf16_rn(pA0) | (bf16_rn(pA1) << 16);
            af1.u[jj] = bf16_rn(pB0) | (bf16_rn(pB1) << 16);
        }

        const ushort* wb = Wp + (size_t)(kcg * 4) * 512 + lane * 8;
        const bf16x8 b0 = *(const bf16x8*)(wb);
        const bf16x8 b1 = *(const bf16x8*)(wb + 512);
        const bf16x8 b2 = *(const bf16x8*)(wb + 1024);
        const bf16x8 b3 = *(const bf16x8*)(wb + 1536);
        a00 = __builtin_amdgcn_mfma_f32_16x16x32_bf16(af0.v, b0, a00, 0, 0, 0);
        a01 = __builtin_amdgcn_mfma_f32_16x16x32_bf16(af0.v, b1, a01, 0, 0, 0);
        a02 = __builtin_amdgcn_mfma_f32_16x16x32_bf16(af0.v, b2, a02, 0, 0, 0);
        a03 = __builtin_amdgcn_mfma_f32_16x16x32_bf16(af0.v, b3, a03, 0, 0, 0);
        a10 = __builtin_amdgcn_mfma_f32_16x16x32_bf16(af1.v, b0, a10, 0, 0, 0);
        a11 = __builtin_amdgcn_mfma_f32_16x16x32_bf16(af1.v, b1, a11, 0, 0, 0);
        a12 = __builtin_amdgcn_mfma_f32_16x16x32_bf16(af1.v, b2, a12, 0, 0, 0);
        a13 = __builtin_amdgcn_mfma_f32_16x16x32_bf16(af1.v, b3, a13, 0, 0, 0);
    }

    // ---- K-split combine; C/D layout: col=lane&15 (o), row=quad*4+reg (batch)
#pragma unroll
    for (int reg = 0; reg < 4; ++reg) {
        const int row = quad * 4 + reg;
        atomicAdd(&Cred[(row)      * CRS +  0 + m], a00[reg]);
        atomicAdd(&Cred[(row)      * CRS + 16 + m], a01[reg]);
        atomicAdd(&Cred[(row)      * CRS + 32 + m], a02[reg]);
        atomicAdd(&Cred[(row)      * CRS + 48 + m], a03[reg]);
        atomicAdd(&Cred[(row + 16) * CRS +  0 + m], a10[reg]);
        atomicAdd(&Cred[(row + 16) * CRS + 16 + m], a11[reg]);
        atomicAdd(&Cred[(row + 16) * CRS + 32 + m], a12[reg]);
        atomicAdd(&Cred[(row + 16) * CRS + 48 + m], a13[reg]);
    }
    __syncthreads();

    // ---- epilogue: g = tanh(C), out = g @ Wout
    {
        const int mm = tid >> 3;         // batch row 0..31
        const int ob = (tid & 7) * 8;    // 8 o's per thread
        float r0 = 0.0f, r1 = 0.0f;
#pragma unroll
        for (int t2 = 0; t2 < 8; ++t2) {
            const int o = ob + t2;
            const float g = fast_tanh(Cred[mm * CRS + o]);
            r0 = fmaf(g, Wout[o * NCLASS + 0], r0);
            r1 = fmaf(g, Wout[o * NCLASS + 1], r1);
        }
#pragma unroll
        for (int off = 4; off > 0; off >>= 1) {
            r0 += __shfl_down(r0, off, 8);
            r1 += __shfl_down(r1, off, 8);
        }
        if ((tid & 7) == 0) {
            outb[mm * NCLASS + 0] = r0;
            outb[mm * NCLASS + 1] = r1;
        }
    }
    __syncthreads();
    if (tid < MT * NCLASS)
        out[bb * NCLASS + tid] = outb[tid];   // coalesced 64-dword store

}

extern "C" void kernel_launch(void* const* d_in, const int* in_sizes, int n_in,
                              void* d_out, int out_size, void* d_ws, size_t ws_size,
                              hipStream_t stream) {
    const float* x    = (const float*)d_in[0];
    const float* Wx   = (const float*)d_in[1];
    const float* ax   = (const float*)d_in[2];
    const float* cx   = (const float*)d_in[3];
    // d_in[4..6] = Wh, ah, ch — dead (comb[:, :HIDDEN] == tanh(x_phi))
    const float* Wc   = (const float*)d_in[7];
    const float* ac   = (const float*)d_in[8];
    const float* cc   = (const float*)d_in[9];
    const float* Wout = (const float*)d_in[10];
    float* out  = (float*)d_out;
    ushort* Wp  = (ushort*)d_ws;    // 40960 bf16 = 80 KiB

    prep_wb<<<dim3(NKC * 4 * 512 / 256), dim3(256), 0, stream>>>(Wc, Wp);
    kan_mfma<<<dim3(BATCH / MT), dim3(64, NW), 0, stream>>>(
        x, Wx, ax, cx, ac, cc, Wout, Wp, out);
}